// Round 9
// baseline (242.544 us; speedup 1.0000x reference)
//
#include <hip/hip_runtime.h>
#include <math.h>

#define N_NODES 20000
#define E_RAW   320000
#define E_TOT   (E_RAW + N_NODES)
#define IN_CH   256
#define HEADS   8
#define HID     32
#define HH      (HEADS*HID)   // 256
#define OUT_CH  40
#define NC2     48            // OUT_CH padded to 3x16
#define NEG     0.2f

typedef __attribute__((ext_vector_type(8))) short  short8;
typedef __attribute__((ext_vector_type(4))) float  floatx4;

// bf16 helpers (bit-level, round-to-nearest-even; values are finite)
__device__ __forceinline__ unsigned short f2bf(float f) {
    unsigned int u = __float_as_uint(f);
    unsigned int r = (u + 0x7FFFu + ((u >> 16) & 1u)) >> 16;
    return (unsigned short)r;
}
__device__ __forceinline__ float bf2f(unsigned short h) {
    return __uint_as_float(((unsigned int)h) << 16);
}

// ---------------- CSR build ----------------

__global__ void zero2_kernel(int* a, int n) {
    int i = blockIdx.x * 256 + threadIdx.x;
    if (i < n) a[i] = 0;
}

// histogram + record each edge's position within its dst bucket
__global__ void hist_kernel(const int* __restrict__ ei, int* __restrict__ deg,
                            int* __restrict__ pos) {
    int e = blockIdx.x * 256 + threadIdx.x;
    if (e >= E_TOT) return;
    int d = (e < E_RAW) ? ei[E_RAW + e] : (e - E_RAW);
    pos[e] = atomicAdd(&deg[d], 1);
}

__global__ __launch_bounds__(1024) void scan_kernel(const int* __restrict__ deg,
                                                    int* __restrict__ offs) {
    __shared__ int part[1024];
    int t = threadIdx.x;
    const int chunk = (N_NODES + 1023) / 1024;  // 20
    int begin = t * chunk;
    int end = begin + chunk; if (end > N_NODES) end = N_NODES;
    if (begin > N_NODES) begin = N_NODES;
    int s = 0;
    for (int i = begin; i < end; i++) s += deg[i];
    part[t] = s;
    __syncthreads();
    for (int off = 1; off < 1024; off <<= 1) {
        int v = (t >= off) ? part[t - off] : 0;
        __syncthreads();
        part[t] += v;
        __syncthreads();
    }
    int run = (t == 0) ? 0 : part[t - 1];
    for (int i = begin; i < end; i++) { offs[i] = run; run += deg[i]; }
    if (t == 1023) offs[N_NODES] = part[1023];
}

__global__ void scatter_kernel(const int* __restrict__ ei, const int* __restrict__ offs,
                               const int* __restrict__ pos, int* __restrict__ csr) {
    int e = blockIdx.x * 256 + threadIdx.x;
    if (e >= E_TOT) return;
    int s, d;
    if (e < E_RAW) { s = ei[e]; d = ei[E_RAW + e]; }
    else           { s = e - E_RAW; d = s; }
    csr[offs[d] + pos[e]] = s;
}

// ---------------- weight prepack: w1t[c][k] (256x256), w2t[c][k] (48x256) ----

__global__ void prepack_kernel(const float* __restrict__ W1,
                               const float* __restrict__ W2,
                               unsigned short* __restrict__ w1t,
                               unsigned short* __restrict__ w2t) {
    int k = threadIdx.x;    // 256
    int b = blockIdx.x;
    if (b < HH) {
        w1t[b * IN_CH + k] = f2bf(W1[(size_t)k * HH + b]);
    } else {
        int c = b - HH;     // 0..47
        w2t[c * HH + k] = (c < OUT_CH) ? f2bf(W2[(size_t)k * OUT_CH + c]) : 0;
    }
}

// ---------------- Layer 1 GEMM: MFMA bf16, 64x64 tile, fused alpha ----------
#define G1_LDK 72
__global__ __launch_bounds__(256) void gemm1(const float* __restrict__ x,
                                             const unsigned short* __restrict__ w1t,
                                             const float* __restrict__ a1s,
                                             const float* __restrict__ a1d,
                                             unsigned short* __restrict__ h1b,
                                             float* __restrict__ as1,
                                             float* __restrict__ ad1) {
    __shared__ unsigned short As[64 * G1_LDK];   // 9 KiB
    __shared__ unsigned short Bs[64 * G1_LDK];   // 9 KiB
    int t = threadIdx.x;
    int wave = t >> 6, lane = t & 63;
    int ln = lane & 15, q = lane >> 4;
    int bm = blockIdx.x >> 2;
    int bn = blockIdx.x & 3;
    int n0 = bm * 64;
    int c0 = bn * 64;

    floatx4 acc[4];
    #pragma unroll
    for (int f = 0; f < 4; f++) acc[f] = (floatx4){0.f, 0.f, 0.f, 0.f};

    int srow = t >> 4, scol = t & 15;

    for (int kc = 0; kc < IN_CH; kc += 64) {
        #pragma unroll
        for (int pp = 0; pp < 4; pp++) {
            int row = srow + pp * 16;
            int n = n0 + row;
            float4 v = (n < N_NODES)
                ? *reinterpret_cast<const float4*>(&x[(size_t)n * IN_CH + kc + scol * 4])
                : make_float4(0.f, 0.f, 0.f, 0.f);
            ushort4 pv;
            pv.x = f2bf(v.x); pv.y = f2bf(v.y); pv.z = f2bf(v.z); pv.w = f2bf(v.w);
            *reinterpret_cast<ushort4*>(&As[row * G1_LDK + scol * 4]) = pv;
            *reinterpret_cast<ushort4*>(&Bs[row * G1_LDK + scol * 4]) =
                *reinterpret_cast<const ushort4*>(&w1t[(size_t)(c0 + row) * IN_CH + kc + scol * 4]);
        }
        __syncthreads();
        #pragma unroll
        for (int ks = 0; ks < 2; ks++) {
            short8 a = *reinterpret_cast<const short8*>(
                &As[(16 * wave + ln) * G1_LDK + ks * 32 + q * 8]);
            #pragma unroll
            for (int f = 0; f < 4; f++) {
                short8 b = *reinterpret_cast<const short8*>(
                    &Bs[(16 * f + ln) * G1_LDK + ks * 32 + q * 8]);
                acc[f] = __builtin_amdgcn_mfma_f32_16x16x32_bf16(a, b, acc[f], 0, 0, 0);
            }
        }
        __syncthreads();
    }

    float Asr[4], Adr[4];
    #pragma unroll
    for (int f = 0; f < 4; f++) {
        Asr[f] = a1s[c0 + 16 * f + ln];
        Adr[f] = a1d[c0 + 16 * f + ln];
    }
    #pragma unroll
    for (int f = 0; f < 4; f++) {
        #pragma unroll
        for (int r = 0; r < 4; r++) {
            int n = n0 + 16 * wave + q * 4 + r;
            if (n < N_NODES)
                h1b[(size_t)n * HH + c0 + 16 * f + ln] = f2bf(acc[f][r]);
        }
    }
    int h0 = c0 >> 5;
    #pragma unroll
    for (int lh = 0; lh < 2; lh++) {
        #pragma unroll
        for (int r = 0; r < 4; r++) {
            float ps = acc[2*lh][r] * Asr[2*lh] + acc[2*lh+1][r] * Asr[2*lh+1];
            float pd = acc[2*lh][r] * Adr[2*lh] + acc[2*lh+1][r] * Adr[2*lh+1];
            ps += __shfl_xor(ps, 1); ps += __shfl_xor(ps, 2);
            ps += __shfl_xor(ps, 4); ps += __shfl_xor(ps, 8);
            pd += __shfl_xor(pd, 1); pd += __shfl_xor(pd, 2);
            pd += __shfl_xor(pd, 4); pd += __shfl_xor(pd, 8);
            int n = n0 + 16 * wave + q * 4 + r;
            if (ln == 0 && n < N_NODES) {
                as1[n * HEADS + h0 + lh] = ps;
                ad1[n * HEADS + h0 + lh] = pd;
            }
        }
    }
}

// ---------------- Layer 1 attention + aggregate + bias + ELU ----------------
// ONE WAVE PER NODE. lane = 4 channels (c4=lane*4, head=lane>>3). Single pass:
// per edge, weight computed in-register (identical within 8-lane head group,
// so denom needs NO reduction), unnormalized accumulate, normalize+bias+ELU
// at the end. No LDS, no barriers, no shuffles.

__global__ __launch_bounds__(256) void aggr1(const unsigned short* __restrict__ h1b,
                                             const float* __restrict__ as1,
                                             const float* __restrict__ ad1,
                                             const float* __restrict__ b1,
                                             const int* __restrict__ offs,
                                             const int* __restrict__ csr,
                                             unsigned short* __restrict__ h2b) {
    int d = blockIdx.x * 4 + (threadIdx.x >> 6);
    int lane = threadIdx.x & 63;
    int h = lane >> 3;
    int c4 = lane * 4;
    int start = offs[d];
    int deg = offs[d + 1] - start;
    float adv = ad1[d * HEADS + h];

    float a0 = 0.f, a1 = 0.f, a2 = 0.f, a3 = 0.f, den = 0.f;
    for (int jj = 0; jj < deg; jj++) {
        int s = csr[start + jj];                       // wave-uniform -> broadcast
        float v = as1[s * HEADS + h] + adv;            // 8 addrs/wave, 1 line
        v = (v > 0.f) ? v : NEG * v;
        float w = __expf(v);
        den += w;
        ushort4 pv = *reinterpret_cast<const ushort4*>(&h1b[(size_t)s * HH + c4]);
        a0 = fmaf(bf2f(pv.x), w, a0);
        a1 = fmaf(bf2f(pv.y), w, a1);
        a2 = fmaf(bf2f(pv.z), w, a2);
        a3 = fmaf(bf2f(pv.w), w, a3);
    }
    float inv = 1.0f / (den + 1e-16f);
    float4 bv = *reinterpret_cast<const float4*>(&b1[c4]);
    float r0 = a0 * inv + bv.x;
    float r1 = a1 * inv + bv.y;
    float r2 = a2 * inv + bv.z;
    float r3 = a3 * inv + bv.w;
    r0 = (r0 > 0.f) ? r0 : (__expf(r0) - 1.f);
    r1 = (r1 > 0.f) ? r1 : (__expf(r1) - 1.f);
    r2 = (r2 > 0.f) ? r2 : (__expf(r2) - 1.f);
    r3 = (r3 > 0.f) ? r3 : (__expf(r3) - 1.f);
    ushort4 ov;
    ov.x = f2bf(r0); ov.y = f2bf(r1); ov.z = f2bf(r2); ov.w = f2bf(r3);
    *reinterpret_cast<ushort4*>(&h2b[(size_t)d * HH + c4]) = ov;
}

// ---------------- Layer 2 GEMM: MFMA bf16, 64 nodes x 48 cols, fused alpha ----
#define G2_LDK 264
__global__ __launch_bounds__(256) void gemm2(const unsigned short* __restrict__ h2b,
                                             const unsigned short* __restrict__ w2t,
                                             const float* __restrict__ a2s,
                                             const float* __restrict__ a2d,
                                             unsigned short* __restrict__ h3b,
                                             float* __restrict__ as2,
                                             float* __restrict__ ad2) {
    __shared__ unsigned short As2[64 * G2_LDK];  // 33 KiB
    __shared__ unsigned short Bs2[NC2 * G2_LDK]; // 24.8 KiB
    int t = threadIdx.x;
    int wave = t >> 6, lane = t & 63;
    int ln = lane & 15, q = lane >> 4;
    int n0 = blockIdx.x * 64;

    {
        int row = t >> 2, seg = t & 3;
        int n = n0 + row;
        #pragma unroll
        for (int i = 0; i < 8; i++) {
            short8 v;
            if (n < N_NODES)
                v = *reinterpret_cast<const short8*>(&h2b[(size_t)n * HH + seg * 64 + i * 8]);
            else
                v = (short8){0,0,0,0,0,0,0,0};
            *reinterpret_cast<short8*>(&As2[row * G2_LDK + seg * 64 + i * 8]) = v;
        }
    }
    for (int u = t; u < NC2 * 32; u += 256) {
        int row = u >> 5;
        int col = (u & 31) * 8;
        *reinterpret_cast<short8*>(&Bs2[row * G2_LDK + col]) =
            *reinterpret_cast<const short8*>(&w2t[(size_t)row * HH + col]);
    }
    __syncthreads();

    floatx4 acc[3];
    #pragma unroll
    for (int f = 0; f < 3; f++) acc[f] = (floatx4){0.f, 0.f, 0.f, 0.f};

    #pragma unroll
    for (int kf = 0; kf < 8; kf++) {
        short8 a = *reinterpret_cast<const short8*>(
            &As2[(16 * wave + ln) * G2_LDK + kf * 32 + q * 8]);
        #pragma unroll
        for (int f = 0; f < 3; f++) {
            short8 b = *reinterpret_cast<const short8*>(
                &Bs2[(16 * f + ln) * G2_LDK + kf * 32 + q * 8]);
            acc[f] = __builtin_amdgcn_mfma_f32_16x16x32_bf16(a, b, acc[f], 0, 0, 0);
        }
    }

    float a2sv[3], a2dv[3];
    #pragma unroll
    for (int f = 0; f < 3; f++) {
        int c = 16 * f + ln;
        a2sv[f] = (c < OUT_CH) ? a2s[c] : 0.f;
        a2dv[f] = (c < OUT_CH) ? a2d[c] : 0.f;
    }
    #pragma unroll
    for (int r = 0; r < 4; r++) {
        int n = n0 + 16 * wave + q * 4 + r;
        float ps = acc[0][r] * a2sv[0] + acc[1][r] * a2sv[1] + acc[2][r] * a2sv[2];
        float pd = acc[0][r] * a2dv[0] + acc[1][r] * a2dv[1] + acc[2][r] * a2dv[2];
        ps += __shfl_xor(ps, 1); ps += __shfl_xor(ps, 2);
        ps += __shfl_xor(ps, 4); ps += __shfl_xor(ps, 8);
        pd += __shfl_xor(pd, 1); pd += __shfl_xor(pd, 2);
        pd += __shfl_xor(pd, 4); pd += __shfl_xor(pd, 8);
        if (n < N_NODES) {
            #pragma unroll
            for (int f = 0; f < 3; f++) {
                int c = 16 * f + ln;
                if (c < OUT_CH)
                    h3b[(size_t)n * OUT_CH + c] = f2bf(acc[f][r]);
            }
            if (ln == 0) { as2[n] = ps; ad2[n] = pd; }
        }
    }
}

// ---------------- Layer 2 attention + aggregate + log_softmax ----------------
// ONE WAVE PER NODE. as2[s] is the SAME address for all lanes (broadcast);
// weight computed redundantly per lane; denom in-register. Lanes 0..39 own
// one channel each. Only the final log_softmax uses shuffles.

__global__ __launch_bounds__(256) void aggr2(const unsigned short* __restrict__ h3b,
                                             const float* __restrict__ as2,
                                             const float* __restrict__ ad2,
                                             const float* __restrict__ b2,
                                             const int* __restrict__ offs,
                                             const int* __restrict__ csr,
                                             float* __restrict__ out) {
    int d = blockIdx.x * 4 + (threadIdx.x >> 6);
    int lane = threadIdx.x & 63;
    int start = offs[d];
    int deg = offs[d + 1] - start;
    float adv = ad2[d];

    float acc = 0.f, den = 0.f;
    for (int jj = 0; jj < deg; jj++) {
        int s = csr[start + jj];                 // uniform
        float v = as2[s] + adv;                  // uniform address -> broadcast
        v = (v > 0.f) ? v : NEG * v;
        float w = __expf(v);
        den += w;
        if (lane < OUT_CH)
            acc = fmaf(bf2f(h3b[(size_t)s * OUT_CH + lane]), w, acc);
    }

    float r = (lane < OUT_CH) ? (acc / (den + 1e-16f) + b2[lane]) : -1e30f;
    float mx = r;
    #pragma unroll
    for (int off = 32; off >= 1; off >>= 1) mx = fmaxf(mx, __shfl_xor(mx, off));
    float ex = (lane < OUT_CH) ? __expf(r - mx) : 0.f;
    float se = ex;
    #pragma unroll
    for (int off = 32; off >= 1; off >>= 1) se += __shfl_xor(se, off);
    if (lane < OUT_CH) out[(size_t)d * OUT_CH + lane] = r - mx - __logf(se);
}

// ---------------- host launcher ----------------

extern "C" void kernel_launch(void* const* d_in, const int* in_sizes, int n_in,
                              void* d_out, int out_size, void* d_ws, size_t ws_size,
                              hipStream_t stream) {
    const float* x   = (const float*)d_in[0];
    const int*   ei  = (const int*)  d_in[1];
    const float* W1  = (const float*)d_in[2];
    const float* a1s = (const float*)d_in[3];
    const float* a1d = (const float*)d_in[4];
    const float* b1  = (const float*)d_in[5];
    const float* W2  = (const float*)d_in[6];
    const float* a2s = (const float*)d_in[7];
    const float* a2d = (const float*)d_in[8];
    const float* b2  = (const float*)d_in[9];
    float* out = (float*)d_out;

    char* p = (char*)d_ws;
    auto alloc = [&](size_t bytes) {
        char* r = p;
        p += (bytes + 255) & ~(size_t)255;
        return r;
    };
    unsigned short* h1b = (unsigned short*)alloc((size_t)N_NODES * HH * 2);
    unsigned short* h2b = (unsigned short*)alloc((size_t)N_NODES * HH * 2);
    unsigned short* h3b = (unsigned short*)alloc((size_t)N_NODES * OUT_CH * 2);
    unsigned short* w1t = (unsigned short*)alloc((size_t)IN_CH * HH * 2);
    unsigned short* w2t = (unsigned short*)alloc((size_t)NC2 * HH * 2);
    float* as1  = (float*)alloc((size_t)N_NODES * HEADS * 4);
    float* ad1  = (float*)alloc((size_t)N_NODES * HEADS * 4);
    float* as2v = (float*)alloc((size_t)N_NODES * 4);
    float* ad2v = (float*)alloc((size_t)N_NODES * 4);
    int* deg    = (int*)alloc((size_t)N_NODES * 4);
    int* pos    = (int*)alloc((size_t)E_TOT * 4);
    int* offs   = (int*)alloc((size_t)(N_NODES + 1) * 4);
    int* csr    = (int*)alloc((size_t)E_TOT * 4);

    zero2_kernel<<<(N_NODES + 255) / 256, 256, 0, stream>>>(deg, N_NODES);
    hist_kernel<<<(E_TOT + 255) / 256, 256, 0, stream>>>(ei, deg, pos);
    scan_kernel<<<1, 1024, 0, stream>>>(deg, offs);
    scatter_kernel<<<(E_TOT + 255) / 256, 256, 0, stream>>>(ei, offs, pos, csr);

    prepack_kernel<<<HH + NC2, IN_CH, 0, stream>>>(W1, W2, w1t, w2t);
    gemm1<<<313 * 4, 256, 0, stream>>>(x, w1t, a1s, a1d, h1b, as1, ad1);
    aggr1<<<N_NODES / 4, 256, 0, stream>>>(h1b, as1, ad1, b1, offs, csr, h2b);
    gemm2<<<313, 256, 0, stream>>>(h2b, w2t, a2s, a2d, h3b, as2v, ad2v);
    aggr2<<<N_NODES / 4, 256, 0, stream>>>(h3b, as2v, ad2v, b2, offs, csr, out);
}

// Round 10
// 200.262 us; speedup vs baseline: 1.2111x; 1.2111x over previous
//
#include <hip/hip_runtime.h>
#include <math.h>

#define N_NODES 20000
#define E_RAW   320000
#define E_TOT   (E_RAW + N_NODES)
#define IN_CH   256
#define HEADS   8
#define HID     32
#define HH      (HEADS*HID)   // 256
#define OUT_CH  40
#define NC2     48            // OUT_CH padded to 3x16
#define NEG     0.2f

typedef __attribute__((ext_vector_type(8))) short  short8;
typedef __attribute__((ext_vector_type(4))) float  floatx4;

// bf16 helpers (bit-level, round-to-nearest-even; values are finite)
__device__ __forceinline__ unsigned short f2bf(float f) {
    unsigned int u = __float_as_uint(f);
    unsigned int r = (u + 0x7FFFu + ((u >> 16) & 1u)) >> 16;
    return (unsigned short)r;
}
__device__ __forceinline__ float bf2f(unsigned short h) {
    return __uint_as_float(((unsigned int)h) << 16);
}
__device__ __forceinline__ float lexp(float v) {
    v = (v > 0.f) ? v : NEG * v;
    return __expf(v);
}

// ---------------- CSR build ----------------

__global__ void zero2_kernel(int* a, int n) {
    int i = blockIdx.x * 256 + threadIdx.x;
    if (i < n) a[i] = 0;
}

__global__ void hist_kernel(const int* __restrict__ ei, int* __restrict__ deg,
                            int* __restrict__ pos) {
    int e = blockIdx.x * 256 + threadIdx.x;
    if (e >= E_TOT) return;
    int d = (e < E_RAW) ? ei[E_RAW + e] : (e - E_RAW);
    pos[e] = atomicAdd(&deg[d], 1);
}

__global__ __launch_bounds__(1024) void scan_kernel(const int* __restrict__ deg,
                                                    int* __restrict__ offs) {
    __shared__ int part[1024];
    int t = threadIdx.x;
    const int chunk = (N_NODES + 1023) / 1024;  // 20
    int begin = t * chunk;
    int end = begin + chunk; if (end > N_NODES) end = N_NODES;
    if (begin > N_NODES) begin = N_NODES;
    int s = 0;
    for (int i = begin; i < end; i++) s += deg[i];
    part[t] = s;
    __syncthreads();
    for (int off = 1; off < 1024; off <<= 1) {
        int v = (t >= off) ? part[t - off] : 0;
        __syncthreads();
        part[t] += v;
        __syncthreads();
    }
    int run = (t == 0) ? 0 : part[t - 1];
    for (int i = begin; i < end; i++) { offs[i] = run; run += deg[i]; }
    if (t == 1023) offs[N_NODES] = part[1023];
}

__global__ void scatter_kernel(const int* __restrict__ ei, const int* __restrict__ offs,
                               const int* __restrict__ pos, int* __restrict__ csr) {
    int e = blockIdx.x * 256 + threadIdx.x;
    if (e >= E_TOT) return;
    int s, d;
    if (e < E_RAW) { s = ei[e]; d = ei[E_RAW + e]; }
    else           { s = e - E_RAW; d = s; }
    csr[offs[d] + pos[e]] = s;
}

// ---------------- weight prepack: w1t[c][k] (256x256), w2t[c][k] (48x256) ----

__global__ void prepack_kernel(const float* __restrict__ W1,
                               const float* __restrict__ W2,
                               unsigned short* __restrict__ w1t,
                               unsigned short* __restrict__ w2t) {
    int k = threadIdx.x;    // 256
    int b = blockIdx.x;
    if (b < HH) {
        w1t[b * IN_CH + k] = f2bf(W1[(size_t)k * HH + b]);
    } else {
        int c = b - HH;     // 0..47
        w2t[c * HH + k] = (c < OUT_CH) ? f2bf(W2[(size_t)k * OUT_CH + c]) : 0;
    }
}

// ---------------- Layer 1 GEMM: MFMA bf16, 64x64 tile, fused alpha ----------
#define G1_LDK 72
__global__ __launch_bounds__(256) void gemm1(const float* __restrict__ x,
                                             const unsigned short* __restrict__ w1t,
                                             const float* __restrict__ a1s,
                                             const float* __restrict__ a1d,
                                             unsigned short* __restrict__ h1b,
                                             float* __restrict__ as1,
                                             float* __restrict__ ad1) {
    __shared__ unsigned short As[64 * G1_LDK];   // 9 KiB
    __shared__ unsigned short Bs[64 * G1_LDK];   // 9 KiB
    int t = threadIdx.x;
    int wave = t >> 6, lane = t & 63;
    int ln = lane & 15, q = lane >> 4;
    int bm = blockIdx.x >> 2;
    int bn = blockIdx.x & 3;
    int n0 = bm * 64;
    int c0 = bn * 64;

    floatx4 acc[4];
    #pragma unroll
    for (int f = 0; f < 4; f++) acc[f] = (floatx4){0.f, 0.f, 0.f, 0.f};

    int srow = t >> 4, scol = t & 15;

    for (int kc = 0; kc < IN_CH; kc += 64) {
        #pragma unroll
        for (int pp = 0; pp < 4; pp++) {
            int row = srow + pp * 16;
            int n = n0 + row;
            float4 v = (n < N_NODES)
                ? *reinterpret_cast<const float4*>(&x[(size_t)n * IN_CH + kc + scol * 4])
                : make_float4(0.f, 0.f, 0.f, 0.f);
            ushort4 pv;
            pv.x = f2bf(v.x); pv.y = f2bf(v.y); pv.z = f2bf(v.z); pv.w = f2bf(v.w);
            *reinterpret_cast<ushort4*>(&As[row * G1_LDK + scol * 4]) = pv;
            *reinterpret_cast<ushort4*>(&Bs[row * G1_LDK + scol * 4]) =
                *reinterpret_cast<const ushort4*>(&w1t[(size_t)(c0 + row) * IN_CH + kc + scol * 4]);
        }
        __syncthreads();
        #pragma unroll
        for (int ks = 0; ks < 2; ks++) {
            short8 a = *reinterpret_cast<const short8*>(
                &As[(16 * wave + ln) * G1_LDK + ks * 32 + q * 8]);
            #pragma unroll
            for (int f = 0; f < 4; f++) {
                short8 b = *reinterpret_cast<const short8*>(
                    &Bs[(16 * f + ln) * G1_LDK + ks * 32 + q * 8]);
                acc[f] = __builtin_amdgcn_mfma_f32_16x16x32_bf16(a, b, acc[f], 0, 0, 0);
            }
        }
        __syncthreads();
    }

    float Asr[4], Adr[4];
    #pragma unroll
    for (int f = 0; f < 4; f++) {
        Asr[f] = a1s[c0 + 16 * f + ln];
        Adr[f] = a1d[c0 + 16 * f + ln];
    }
    #pragma unroll
    for (int f = 0; f < 4; f++) {
        #pragma unroll
        for (int r = 0; r < 4; r++) {
            int n = n0 + 16 * wave + q * 4 + r;
            if (n < N_NODES)
                h1b[(size_t)n * HH + c0 + 16 * f + ln] = f2bf(acc[f][r]);
        }
    }
    int h0 = c0 >> 5;
    #pragma unroll
    for (int lh = 0; lh < 2; lh++) {
        #pragma unroll
        for (int r = 0; r < 4; r++) {
            float ps = acc[2*lh][r] * Asr[2*lh] + acc[2*lh+1][r] * Asr[2*lh+1];
            float pd = acc[2*lh][r] * Adr[2*lh] + acc[2*lh+1][r] * Adr[2*lh+1];
            ps += __shfl_xor(ps, 1); ps += __shfl_xor(ps, 2);
            ps += __shfl_xor(ps, 4); ps += __shfl_xor(ps, 8);
            pd += __shfl_xor(pd, 1); pd += __shfl_xor(pd, 2);
            pd += __shfl_xor(pd, 4); pd += __shfl_xor(pd, 8);
            int n = n0 + 16 * wave + q * 4 + r;
            if (ln == 0 && n < N_NODES) {
                as1[n * HEADS + h0 + lh] = ps;
                ad1[n * HEADS + h0 + lh] = pd;
            }
        }
    }
}

// ---------------- Layer 1 attention + aggregate + bias + ELU ----------------
// ONE WAVE PER NODE, lane = 4 channels. Manual 4-edge unroll: all group loads
// (4 csr + 4 as1 + 4 feature rows) issue before any use -> 4 gathers in flight.

__global__ __launch_bounds__(256) void aggr1(const unsigned short* __restrict__ h1b,
                                             const float* __restrict__ as1,
                                             const float* __restrict__ ad1,
                                             const float* __restrict__ b1,
                                             const int* __restrict__ offs,
                                             const int* __restrict__ csr,
                                             unsigned short* __restrict__ h2b) {
    int d = blockIdx.x * 4 + (threadIdx.x >> 6);
    int lane = threadIdx.x & 63;
    int h = lane >> 3;
    int c4 = lane * 4;
    int start = offs[d];
    int deg = offs[d + 1] - start;
    float adv = ad1[d * HEADS + h];

    float a0 = 0.f, a1 = 0.f, a2 = 0.f, a3 = 0.f, den = 0.f;
    int jj = 0;
    for (; jj + 4 <= deg; jj += 4) {
        int s0 = csr[start + jj + 0];
        int s1 = csr[start + jj + 1];
        int s2 = csr[start + jj + 2];
        int s3 = csr[start + jj + 3];
        float e0 = as1[s0 * HEADS + h];
        float e1 = as1[s1 * HEADS + h];
        float e2 = as1[s2 * HEADS + h];
        float e3 = as1[s3 * HEADS + h];
        ushort4 p0 = *reinterpret_cast<const ushort4*>(&h1b[(size_t)s0 * HH + c4]);
        ushort4 p1 = *reinterpret_cast<const ushort4*>(&h1b[(size_t)s1 * HH + c4]);
        ushort4 p2 = *reinterpret_cast<const ushort4*>(&h1b[(size_t)s2 * HH + c4]);
        ushort4 p3 = *reinterpret_cast<const ushort4*>(&h1b[(size_t)s3 * HH + c4]);
        float w0 = lexp(e0 + adv);
        float w1 = lexp(e1 + adv);
        float w2 = lexp(e2 + adv);
        float w3 = lexp(e3 + adv);
        den += (w0 + w1) + (w2 + w3);
        a0 = fmaf(bf2f(p0.x), w0, a0); a1 = fmaf(bf2f(p0.y), w0, a1);
        a2 = fmaf(bf2f(p0.z), w0, a2); a3 = fmaf(bf2f(p0.w), w0, a3);
        a0 = fmaf(bf2f(p1.x), w1, a0); a1 = fmaf(bf2f(p1.y), w1, a1);
        a2 = fmaf(bf2f(p1.z), w1, a2); a3 = fmaf(bf2f(p1.w), w1, a3);
        a0 = fmaf(bf2f(p2.x), w2, a0); a1 = fmaf(bf2f(p2.y), w2, a1);
        a2 = fmaf(bf2f(p2.z), w2, a2); a3 = fmaf(bf2f(p2.w), w2, a3);
        a0 = fmaf(bf2f(p3.x), w3, a0); a1 = fmaf(bf2f(p3.y), w3, a1);
        a2 = fmaf(bf2f(p3.z), w3, a2); a3 = fmaf(bf2f(p3.w), w3, a3);
    }
    for (; jj < deg; jj++) {
        int s = csr[start + jj];
        float w = lexp(as1[s * HEADS + h] + adv);
        den += w;
        ushort4 pv = *reinterpret_cast<const ushort4*>(&h1b[(size_t)s * HH + c4]);
        a0 = fmaf(bf2f(pv.x), w, a0);
        a1 = fmaf(bf2f(pv.y), w, a1);
        a2 = fmaf(bf2f(pv.z), w, a2);
        a3 = fmaf(bf2f(pv.w), w, a3);
    }
    float inv = 1.0f / (den + 1e-16f);
    float4 bv = *reinterpret_cast<const float4*>(&b1[c4]);
    float r0 = a0 * inv + bv.x;
    float r1 = a1 * inv + bv.y;
    float r2 = a2 * inv + bv.z;
    float r3 = a3 * inv + bv.w;
    r0 = (r0 > 0.f) ? r0 : (__expf(r0) - 1.f);
    r1 = (r1 > 0.f) ? r1 : (__expf(r1) - 1.f);
    r2 = (r2 > 0.f) ? r2 : (__expf(r2) - 1.f);
    r3 = (r3 > 0.f) ? r3 : (__expf(r3) - 1.f);
    ushort4 ov;
    ov.x = f2bf(r0); ov.y = f2bf(r1); ov.z = f2bf(r2); ov.w = f2bf(r3);
    *reinterpret_cast<ushort4*>(&h2b[(size_t)d * HH + c4]) = ov;
}

// ---------------- Layer 2 GEMM: MFMA bf16, 64 nodes x 48 cols, fused alpha ----
#define G2_LDK 264
__global__ __launch_bounds__(256) void gemm2(const unsigned short* __restrict__ h2b,
                                             const unsigned short* __restrict__ w2t,
                                             const float* __restrict__ a2s,
                                             const float* __restrict__ a2d,
                                             unsigned short* __restrict__ h3b,
                                             float* __restrict__ as2,
                                             float* __restrict__ ad2) {
    __shared__ unsigned short As2[64 * G2_LDK];  // 33 KiB
    __shared__ unsigned short Bs2[NC2 * G2_LDK]; // 24.8 KiB
    int t = threadIdx.x;
    int wave = t >> 6, lane = t & 63;
    int ln = lane & 15, q = lane >> 4;
    int n0 = blockIdx.x * 64;

    {
        int row = t >> 2, seg = t & 3;
        int n = n0 + row;
        #pragma unroll
        for (int i = 0; i < 8; i++) {
            short8 v;
            if (n < N_NODES)
                v = *reinterpret_cast<const short8*>(&h2b[(size_t)n * HH + seg * 64 + i * 8]);
            else
                v = (short8){0,0,0,0,0,0,0,0};
            *reinterpret_cast<short8*>(&As2[row * G2_LDK + seg * 64 + i * 8]) = v;
        }
    }
    for (int u = t; u < NC2 * 32; u += 256) {
        int row = u >> 5;
        int col = (u & 31) * 8;
        *reinterpret_cast<short8*>(&Bs2[row * G2_LDK + col]) =
            *reinterpret_cast<const short8*>(&w2t[(size_t)row * HH + col]);
    }
    __syncthreads();

    floatx4 acc[3];
    #pragma unroll
    for (int f = 0; f < 3; f++) acc[f] = (floatx4){0.f, 0.f, 0.f, 0.f};

    #pragma unroll
    for (int kf = 0; kf < 8; kf++) {
        short8 a = *reinterpret_cast<const short8*>(
            &As2[(16 * wave + ln) * G2_LDK + kf * 32 + q * 8]);
        #pragma unroll
        for (int f = 0; f < 3; f++) {
            short8 b = *reinterpret_cast<const short8*>(
                &Bs2[(16 * f + ln) * G2_LDK + kf * 32 + q * 8]);
            acc[f] = __builtin_amdgcn_mfma_f32_16x16x32_bf16(a, b, acc[f], 0, 0, 0);
        }
    }

    float a2sv[3], a2dv[3];
    #pragma unroll
    for (int f = 0; f < 3; f++) {
        int c = 16 * f + ln;
        a2sv[f] = (c < OUT_CH) ? a2s[c] : 0.f;
        a2dv[f] = (c < OUT_CH) ? a2d[c] : 0.f;
    }
    #pragma unroll
    for (int r = 0; r < 4; r++) {
        int n = n0 + 16 * wave + q * 4 + r;
        float ps = acc[0][r] * a2sv[0] + acc[1][r] * a2sv[1] + acc[2][r] * a2sv[2];
        float pd = acc[0][r] * a2dv[0] + acc[1][r] * a2dv[1] + acc[2][r] * a2dv[2];
        ps += __shfl_xor(ps, 1); ps += __shfl_xor(ps, 2);
        ps += __shfl_xor(ps, 4); ps += __shfl_xor(ps, 8);
        pd += __shfl_xor(pd, 1); pd += __shfl_xor(pd, 2);
        pd += __shfl_xor(pd, 4); pd += __shfl_xor(pd, 8);
        if (n < N_NODES) {
            #pragma unroll
            for (int f = 0; f < 3; f++) {
                int c = 16 * f + ln;
                if (c < OUT_CH)
                    h3b[(size_t)n * OUT_CH + c] = f2bf(acc[f][r]);
            }
            if (ln == 0) { as2[n] = ps; ad2[n] = pd; }
        }
    }
}

// ---------------- Layer 2 attention + aggregate + log_softmax ----------------
// ONE WAVE PER NODE, 4-edge unrolled for MLP; lanes 0..39 own one channel.

__global__ __launch_bounds__(256) void aggr2(const unsigned short* __restrict__ h3b,
                                             const float* __restrict__ as2,
                                             const float* __restrict__ ad2,
                                             const float* __restrict__ b2,
                                             const int* __restrict__ offs,
                                             const int* __restrict__ csr,
                                             float* __restrict__ out) {
    int d = blockIdx.x * 4 + (threadIdx.x >> 6);
    int lane = threadIdx.x & 63;
    int start = offs[d];
    int deg = offs[d + 1] - start;
    float adv = ad2[d];
    bool ok = (lane < OUT_CH);
    int cl = ok ? lane : 0;

    float acc = 0.f, den = 0.f;
    int jj = 0;
    for (; jj + 4 <= deg; jj += 4) {
        int s0 = csr[start + jj + 0];
        int s1 = csr[start + jj + 1];
        int s2 = csr[start + jj + 2];
        int s3 = csr[start + jj + 3];
        float e0 = as2[s0], e1 = as2[s1], e2 = as2[s2], e3 = as2[s3];
        unsigned short q0 = h3b[(size_t)s0 * OUT_CH + cl];
        unsigned short q1 = h3b[(size_t)s1 * OUT_CH + cl];
        unsigned short q2 = h3b[(size_t)s2 * OUT_CH + cl];
        unsigned short q3 = h3b[(size_t)s3 * OUT_CH + cl];
        float w0 = lexp(e0 + adv);
        float w1 = lexp(e1 + adv);
        float w2 = lexp(e2 + adv);
        float w3 = lexp(e3 + adv);
        den += (w0 + w1) + (w2 + w3);
        acc = fmaf(bf2f(q0), w0, acc);
        acc = fmaf(bf2f(q1), w1, acc);
        acc = fmaf(bf2f(q2), w2, acc);
        acc = fmaf(bf2f(q3), w3, acc);
    }
    for (; jj < deg; jj++) {
        int s = csr[start + jj];
        float w = lexp(as2[s] + adv);
        den += w;
        acc = fmaf(bf2f(h3b[(size_t)s * OUT_CH + cl]), w, acc);
    }

    float r = ok ? (acc / (den + 1e-16f) + b2[lane]) : -1e30f;
    float mx = r;
    #pragma unroll
    for (int off = 32; off >= 1; off >>= 1) mx = fmaxf(mx, __shfl_xor(mx, off));
    float ex = ok ? __expf(r - mx) : 0.f;
    float se = ex;
    #pragma unroll
    for (int off = 32; off >= 1; off >>= 1) se += __shfl_xor(se, off);
    if (ok) out[(size_t)d * OUT_CH + lane] = r - mx - __logf(se);
}

// ---------------- host launcher ----------------

extern "C" void kernel_launch(void* const* d_in, const int* in_sizes, int n_in,
                              void* d_out, int out_size, void* d_ws, size_t ws_size,
                              hipStream_t stream) {
    const float* x   = (const float*)d_in[0];
    const int*   ei  = (const int*)  d_in[1];
    const float* W1  = (const float*)d_in[2];
    const float* a1s = (const float*)d_in[3];
    const float* a1d = (const float*)d_in[4];
    const float* b1  = (const float*)d_in[5];
    const float* W2  = (const float*)d_in[6];
    const float* a2s = (const float*)d_in[7];
    const float* a2d = (const float*)d_in[8];
    const float* b2  = (const float*)d_in[9];
    float* out = (float*)d_out;

    char* p = (char*)d_ws;
    auto alloc = [&](size_t bytes) {
        char* r = p;
        p += (bytes + 255) & ~(size_t)255;
        return r;
    };
    unsigned short* h1b = (unsigned short*)alloc((size_t)N_NODES * HH * 2);
    unsigned short* h2b = (unsigned short*)alloc((size_t)N_NODES * HH * 2);
    unsigned short* h3b = (unsigned short*)alloc((size_t)N_NODES * OUT_CH * 2);
    unsigned short* w1t = (unsigned short*)alloc((size_t)IN_CH * HH * 2);
    unsigned short* w2t = (unsigned short*)alloc((size_t)NC2 * HH * 2);
    float* as1  = (float*)alloc((size_t)N_NODES * HEADS * 4);
    float* ad1  = (float*)alloc((size_t)N_NODES * HEADS * 4);
    float* as2v = (float*)alloc((size_t)N_NODES * 4);
    float* ad2v = (float*)alloc((size_t)N_NODES * 4);
    int* deg    = (int*)alloc((size_t)N_NODES * 4);
    int* pos    = (int*)alloc((size_t)E_TOT * 4);
    int* offs   = (int*)alloc((size_t)(N_NODES + 1) * 4);
    int* csr    = (int*)alloc((size_t)E_TOT * 4);

    zero2_kernel<<<(N_NODES + 255) / 256, 256, 0, stream>>>(deg, N_NODES);
    hist_kernel<<<(E_TOT + 255) / 256, 256, 0, stream>>>(ei, deg, pos);
    scan_kernel<<<1, 1024, 0, stream>>>(deg, offs);
    scatter_kernel<<<(E_TOT + 255) / 256, 256, 0, stream>>>(ei, offs, pos, csr);

    prepack_kernel<<<HH + NC2, IN_CH, 0, stream>>>(W1, W2, w1t, w2t);
    gemm1<<<313 * 4, 256, 0, stream>>>(x, w1t, a1s, a1d, h1b, as1, ad1);
    aggr1<<<N_NODES / 4, 256, 0, stream>>>(h1b, as1, ad1, b1, offs, csr, h2b);
    gemm2<<<313, 256, 0, stream>>>(h2b, w2t, a2s, a2d, h3b, as2v, ad2v);
    aggr2<<<N_NODES / 4, 256, 0, stream>>>(h3b, as2v, ad2v, b2, offs, csr, out);
}

// Round 12
// 179.303 us; speedup vs baseline: 1.3527x; 1.1169x over previous
//
#include <hip/hip_runtime.h>
#include <math.h>

#define N_NODES 20000
#define E_RAW   320000
#define E_TOT   (E_RAW + N_NODES)
#define IN_CH   256
#define HEADS   8
#define HID     32
#define HH      (HEADS*HID)   // 256
#define OUT_CH  40
#define NC2     48            // OUT_CH padded to 3x16
#define NEG     0.2f

typedef __attribute__((ext_vector_type(8))) short  short8;
typedef __attribute__((ext_vector_type(4))) float  floatx4;

// bf16 helpers (bit-level, round-to-nearest-even; values are finite)
__device__ __forceinline__ unsigned short f2bf(float f) {
    unsigned int u = __float_as_uint(f);
    unsigned int r = (u + 0x7FFFu + ((u >> 16) & 1u)) >> 16;
    return (unsigned short)r;
}
__device__ __forceinline__ float bf2f(unsigned short h) {
    return __uint_as_float(((unsigned int)h) << 16);
}
__device__ __forceinline__ float lexp(float v) {
    v = (v > 0.f) ? v : NEG * v;
    return __expf(v);
}

// ---------------- setup: zero deg + prepack w1t/w2t (fused) ----------------

__global__ void setup_kernel(const float* __restrict__ W1,
                             const float* __restrict__ W2,
                             unsigned short* __restrict__ w1t,
                             unsigned short* __restrict__ w2t,
                             int* __restrict__ deg) {
    int b = blockIdx.x;
    int t = threadIdx.x;
    if (b < 79) {                       // zero deg[20000]
        int i = b * 256 + t;
        if (i < N_NODES) deg[i] = 0;
    } else if (b < 79 + HH) {           // w1t[c][k]
        int c = b - 79;
        w1t[c * IN_CH + t] = f2bf(W1[(size_t)t * HH + c]);
    } else {                            // w2t[c][k]
        int c = b - 79 - HH;            // 0..47
        w2t[c * HH + t] = (c < OUT_CH) ? f2bf(W2[(size_t)t * OUT_CH + c]) : 0;
    }
}

// ---------------- CSR build ----------------

__global__ void hist_kernel(const int* __restrict__ ei, int* __restrict__ deg,
                            int* __restrict__ pos) {
    int e = blockIdx.x * 256 + threadIdx.x;
    if (e >= E_TOT) return;
    int d = (e < E_RAW) ? ei[E_RAW + e] : (e - E_RAW);
    pos[e] = atomicAdd(&deg[d], 1);
}

__global__ __launch_bounds__(1024) void scan_kernel(const int* __restrict__ deg,
                                                    int* __restrict__ offs) {
    __shared__ int part[1024];
    int t = threadIdx.x;
    const int chunk = 20;               // t*20; N_NODES % 20 == 0 -> chunks all-in or all-out
    int begin = t * chunk;
    bool in = (begin < N_NODES);        // t < 1000
    int loc[20];
    if (in) {
        #pragma unroll
        for (int v4 = 0; v4 < 5; v4++) {
            int4 v = *reinterpret_cast<const int4*>(&deg[begin + v4 * 4]);
            loc[v4*4+0] = v.x; loc[v4*4+1] = v.y; loc[v4*4+2] = v.z; loc[v4*4+3] = v.w;
        }
    } else {
        #pragma unroll
        for (int i = 0; i < 20; i++) loc[i] = 0;
    }
    int s = 0;
    #pragma unroll
    for (int i = 0; i < 20; i++) s += loc[i];
    part[t] = s;
    __syncthreads();
    for (int off = 1; off < 1024; off <<= 1) {
        int v = (t >= off) ? part[t - off] : 0;
        __syncthreads();
        part[t] += v;
        __syncthreads();
    }
    int run = (t == 0) ? 0 : part[t - 1];
    if (in) {
        #pragma unroll
        for (int i = 0; i < 20; i++) { offs[begin + i] = run; run += loc[i]; }
    }
    if (t == 1023) offs[N_NODES] = part[1023];
}

__global__ void scatter_kernel(const int* __restrict__ ei, const int* __restrict__ offs,
                               const int* __restrict__ pos, int* __restrict__ csr) {
    int e = blockIdx.x * 256 + threadIdx.x;
    if (e >= E_TOT) return;
    int s, d;
    if (e < E_RAW) { s = ei[e]; d = ei[E_RAW + e]; }
    else           { s = e - E_RAW; d = s; }
    csr[offs[d] + pos[e]] = s;
}

// ---------------- Layer 1 GEMM: MFMA bf16, 64x128 tile, fused alpha ---------
// grid = 313*2; block 256 = 4 waves. Wave w: rows [16w,16w+16), 8 col-frags.
// 128 cols = 4 whole heads -> alpha dots fully block-local.
#define G1_LDK 72
__global__ __launch_bounds__(256) void gemm1(const float* __restrict__ x,
                                             const unsigned short* __restrict__ w1t,
                                             const float* __restrict__ a1s,
                                             const float* __restrict__ a1d,
                                             unsigned short* __restrict__ h1b,
                                             float* __restrict__ as1,
                                             float* __restrict__ ad1) {
    __shared__ unsigned short As[64 * G1_LDK];    // 9 KiB
    __shared__ unsigned short Bs[128 * G1_LDK];   // 18 KiB
    int t = threadIdx.x;
    int wave = t >> 6, lane = t & 63;
    int ln = lane & 15, q = lane >> 4;
    int bm = blockIdx.x >> 1;
    int bn = blockIdx.x & 1;
    int n0 = bm * 64;
    int c0 = bn * 128;

    floatx4 acc[8];
    #pragma unroll
    for (int f = 0; f < 8; f++) acc[f] = (floatx4){0.f, 0.f, 0.f, 0.f};

    int srow = t >> 4, scol = t & 15;

    for (int kc = 0; kc < IN_CH; kc += 64) {
        #pragma unroll
        for (int pp = 0; pp < 4; pp++) {
            int row = srow + pp * 16;
            int n = n0 + row;
            float4 v = (n < N_NODES)
                ? *reinterpret_cast<const float4*>(&x[(size_t)n * IN_CH + kc + scol * 4])
                : make_float4(0.f, 0.f, 0.f, 0.f);
            ushort4 pv;
            pv.x = f2bf(v.x); pv.y = f2bf(v.y); pv.z = f2bf(v.z); pv.w = f2bf(v.w);
            *reinterpret_cast<ushort4*>(&As[row * G1_LDK + scol * 4]) = pv;
        }
        #pragma unroll
        for (int pp = 0; pp < 8; pp++) {
            int row = srow + pp * 16;      // 0..127
            *reinterpret_cast<ushort4*>(&Bs[row * G1_LDK + scol * 4]) =
                *reinterpret_cast<const ushort4*>(&w1t[(size_t)(c0 + row) * IN_CH + kc + scol * 4]);
        }
        __syncthreads();
        #pragma unroll
        for (int ks = 0; ks < 2; ks++) {
            short8 a = *reinterpret_cast<const short8*>(
                &As[(16 * wave + ln) * G1_LDK + ks * 32 + q * 8]);
            #pragma unroll
            for (int f = 0; f < 8; f++) {
                short8 b = *reinterpret_cast<const short8*>(
                    &Bs[(16 * f + ln) * G1_LDK + ks * 32 + q * 8]);
                acc[f] = __builtin_amdgcn_mfma_f32_16x16x32_bf16(a, b, acc[f], 0, 0, 0);
            }
        }
        __syncthreads();
    }

    float Asr[8], Adr[8];
    #pragma unroll
    for (int f = 0; f < 8; f++) {
        Asr[f] = a1s[c0 + 16 * f + ln];
        Adr[f] = a1d[c0 + 16 * f + ln];
    }
    #pragma unroll
    for (int f = 0; f < 8; f++) {
        #pragma unroll
        for (int r = 0; r < 4; r++) {
            int n = n0 + 16 * wave + q * 4 + r;
            if (n < N_NODES)
                h1b[(size_t)n * HH + c0 + 16 * f + ln] = f2bf(acc[f][r]);
        }
    }
    int h0 = c0 >> 5;   // first head of this block (4 heads/block)
    #pragma unroll
    for (int lh = 0; lh < 4; lh++) {
        #pragma unroll
        for (int r = 0; r < 4; r++) {
            float ps = acc[2*lh][r] * Asr[2*lh] + acc[2*lh+1][r] * Asr[2*lh+1];
            float pd = acc[2*lh][r] * Adr[2*lh] + acc[2*lh+1][r] * Adr[2*lh+1];
            ps += __shfl_xor(ps, 1); ps += __shfl_xor(ps, 2);
            ps += __shfl_xor(ps, 4); ps += __shfl_xor(ps, 8);
            pd += __shfl_xor(pd, 1); pd += __shfl_xor(pd, 2);
            pd += __shfl_xor(pd, 4); pd += __shfl_xor(pd, 8);
            int n = n0 + 16 * wave + q * 4 + r;
            if (ln == 0 && n < N_NODES) {
                as1[n * HEADS + h0 + lh] = ps;
                ad1[n * HEADS + h0 + lh] = pd;
            }
        }
    }
}

// ---------------- Layer 1 attention + aggregate + bias + ELU ----------------
// ONE WAVE PER NODE, lane = 4 channels. 8-edge unroll for MLP.

__global__ __launch_bounds__(256) void aggr1(const unsigned short* __restrict__ h1b,
                                             const float* __restrict__ as1,
                                             const float* __restrict__ ad1,
                                             const float* __restrict__ b1,
                                             const int* __restrict__ offs,
                                             const int* __restrict__ csr,
                                             unsigned short* __restrict__ h2b) {
    int d = blockIdx.x * 4 + (threadIdx.x >> 6);
    int lane = threadIdx.x & 63;
    int h = lane >> 3;
    int c4 = lane * 4;
    int start = offs[d];
    int deg = offs[d + 1] - start;
    float adv = ad1[d * HEADS + h];

    float a0 = 0.f, a1 = 0.f, a2 = 0.f, a3 = 0.f, den = 0.f;
    int jj = 0;
    for (; jj + 8 <= deg; jj += 8) {
        int s[8];
        #pragma unroll
        for (int i = 0; i < 8; i++) s[i] = csr[start + jj + i];
        float e[8];
        #pragma unroll
        for (int i = 0; i < 8; i++) e[i] = as1[s[i] * HEADS + h];
        ushort4 pv[8];
        #pragma unroll
        for (int i = 0; i < 8; i++)
            pv[i] = *reinterpret_cast<const ushort4*>(&h1b[(size_t)s[i] * HH + c4]);
        #pragma unroll
        for (int i = 0; i < 8; i++) {
            float w = lexp(e[i] + adv);
            den += w;
            a0 = fmaf(bf2f(pv[i].x), w, a0);
            a1 = fmaf(bf2f(pv[i].y), w, a1);
            a2 = fmaf(bf2f(pv[i].z), w, a2);
            a3 = fmaf(bf2f(pv[i].w), w, a3);
        }
    }
    for (; jj < deg; jj++) {
        int s = csr[start + jj];
        float w = lexp(as1[s * HEADS + h] + adv);
        den += w;
        ushort4 pv = *reinterpret_cast<const ushort4*>(&h1b[(size_t)s * HH + c4]);
        a0 = fmaf(bf2f(pv.x), w, a0);
        a1 = fmaf(bf2f(pv.y), w, a1);
        a2 = fmaf(bf2f(pv.z), w, a2);
        a3 = fmaf(bf2f(pv.w), w, a3);
    }
    float inv = 1.0f / (den + 1e-16f);
    float4 bv = *reinterpret_cast<const float4*>(&b1[c4]);
    float r0 = a0 * inv + bv.x;
    float r1 = a1 * inv + bv.y;
    float r2 = a2 * inv + bv.z;
    float r3 = a3 * inv + bv.w;
    r0 = (r0 > 0.f) ? r0 : (__expf(r0) - 1.f);
    r1 = (r1 > 0.f) ? r1 : (__expf(r1) - 1.f);
    r2 = (r2 > 0.f) ? r2 : (__expf(r2) - 1.f);
    r3 = (r3 > 0.f) ? r3 : (__expf(r3) - 1.f);
    ushort4 ov;
    ov.x = f2bf(r0); ov.y = f2bf(r1); ov.z = f2bf(r2); ov.w = f2bf(r3);
    *reinterpret_cast<ushort4*>(&h2b[(size_t)d * HH + c4]) = ov;
}

// ---------------- Layer 2 GEMM: MFMA bf16, 64 nodes x 48 cols, fused alpha ----
#define G2_LDK 264
__global__ __launch_bounds__(256) void gemm2(const unsigned short* __restrict__ h2b,
                                             const unsigned short* __restrict__ w2t,
                                             const float* __restrict__ a2s,
                                             const float* __restrict__ a2d,
                                             unsigned short* __restrict__ h3b,
                                             float* __restrict__ as2,
                                             float* __restrict__ ad2) {
    __shared__ unsigned short As2[64 * G2_LDK];  // 33 KiB
    __shared__ unsigned short Bs2[NC2 * G2_LDK]; // 24.8 KiB
    int t = threadIdx.x;
    int wave = t >> 6, lane = t & 63;
    int ln = lane & 15, q = lane >> 4;
    int n0 = blockIdx.x * 64;

    {
        int row = t >> 2, seg = t & 3;
        int n = n0 + row;
        #pragma unroll
        for (int i = 0; i < 8; i++) {
            short8 v;
            if (n < N_NODES)
                v = *reinterpret_cast<const short8*>(&h2b[(size_t)n * HH + seg * 64 + i * 8]);
            else
                v = (short8){0,0,0,0,0,0,0,0};
            *reinterpret_cast<short8*>(&As2[row * G2_LDK + seg * 64 + i * 8]) = v;
        }
    }
    for (int u = t; u < NC2 * 32; u += 256) {
        int row = u >> 5;
        int col = (u & 31) * 8;
        *reinterpret_cast<short8*>(&Bs2[row * G2_LDK + col]) =
            *reinterpret_cast<const short8*>(&w2t[(size_t)row * HH + col]);
    }
    __syncthreads();

    floatx4 acc[3];
    #pragma unroll
    for (int f = 0; f < 3; f++) acc[f] = (floatx4){0.f, 0.f, 0.f, 0.f};

    #pragma unroll
    for (int kf = 0; kf < 8; kf++) {
        short8 a = *reinterpret_cast<const short8*>(
            &As2[(16 * wave + ln) * G2_LDK + kf * 32 + q * 8]);
        #pragma unroll
        for (int f = 0; f < 3; f++) {
            short8 b = *reinterpret_cast<const short8*>(
                &Bs2[(16 * f + ln) * G2_LDK + kf * 32 + q * 8]);
            acc[f] = __builtin_amdgcn_mfma_f32_16x16x32_bf16(a, b, acc[f], 0, 0, 0);
        }
    }

    float a2sv[3], a2dv[3];
    #pragma unroll
    for (int f = 0; f < 3; f++) {
        int c = 16 * f + ln;
        a2sv[f] = (c < OUT_CH) ? a2s[c] : 0.f;
        a2dv[f] = (c < OUT_CH) ? a2d[c] : 0.f;
    }
    #pragma unroll
    for (int r = 0; r < 4; r++) {
        int n = n0 + 16 * wave + q * 4 + r;
        float ps = acc[0][r] * a2sv[0] + acc[1][r] * a2sv[1] + acc[2][r] * a2sv[2];
        float pd = acc[0][r] * a2dv[0] + acc[1][r] * a2dv[1] + acc[2][r] * a2dv[2];
        ps += __shfl_xor(ps, 1); ps += __shfl_xor(ps, 2);
        ps += __shfl_xor(ps, 4); ps += __shfl_xor(ps, 8);
        pd += __shfl_xor(pd, 1); pd += __shfl_xor(pd, 2);
        pd += __shfl_xor(pd, 4); pd += __shfl_xor(pd, 8);
        if (n < N_NODES) {
            #pragma unroll
            for (int f = 0; f < 3; f++) {
                int c = 16 * f + ln;
                if (c < OUT_CH)
                    h3b[(size_t)n * OUT_CH + c] = f2bf(acc[f][r]);
            }
            if (ln == 0) { as2[n] = ps; ad2[n] = pd; }
        }
    }
}

// ---------------- Layer 2 attention + aggregate + log_softmax ----------------
// ONE WAVE PER NODE, 8-edge unrolled; lanes 0..39 own one channel.

__global__ __launch_bounds__(256) void aggr2(const unsigned short* __restrict__ h3b,
                                             const float* __restrict__ as2,
                                             const float* __restrict__ ad2,
                                             const float* __restrict__ b2,
                                             const int* __restrict__ offs,
                                             const int* __restrict__ csr,
                                             float* __restrict__ out) {
    int d = blockIdx.x * 4 + (threadIdx.x >> 6);
    int lane = threadIdx.x & 63;
    int start = offs[d];
    int deg = offs[d + 1] - start;
    float adv = ad2[d];
    bool ok = (lane < OUT_CH);
    int cl = ok ? lane : 0;

    float acc = 0.f, den = 0.f;
    int jj = 0;
    for (; jj + 8 <= deg; jj += 8) {
        int s[8];
        #pragma unroll
        for (int i = 0; i < 8; i++) s[i] = csr[start + jj + i];
        float e[8];
        #pragma unroll
        for (int i = 0; i < 8; i++) e[i] = as2[s[i]];
        unsigned short qv[8];
        #pragma unroll
        for (int i = 0; i < 8; i++) qv[i] = h3b[(size_t)s[i] * OUT_CH + cl];
        #pragma unroll
        for (int i = 0; i < 8; i++) {
            float w = lexp(e[i] + adv);
            den += w;
            acc = fmaf(bf2f(qv[i]), w, acc);
        }
    }
    for (; jj < deg; jj++) {
        int s = csr[start + jj];
        float w = lexp(as2[s] + adv);
        den += w;
        acc = fmaf(bf2f(h3b[(size_t)s * OUT_CH + cl]), w, acc);
    }

    float r = ok ? (acc / (den + 1e-16f) + b2[lane]) : -1e30f;
    float mx = r;
    #pragma unroll
    for (int off = 32; off >= 1; off >>= 1) mx = fmaxf(mx, __shfl_xor(mx, off));
    float ex = ok ? __expf(r - mx) : 0.f;
    float se = ex;
    #pragma unroll
    for (int off = 32; off >= 1; off >>= 1) se += __shfl_xor(se, off);
    if (ok) out[(size_t)d * OUT_CH + lane] = r - mx - __logf(se);
}

// ---------------- host launcher ----------------

extern "C" void kernel_launch(void* const* d_in, const int* in_sizes, int n_in,
                              void* d_out, int out_size, void* d_ws, size_t ws_size,
                              hipStream_t stream) {
    const float* x   = (const float*)d_in[0];
    const int*   ei  = (const int*)  d_in[1];
    const float* W1  = (const float*)d_in[2];
    const float* a1s = (const float*)d_in[3];
    const float* a1d = (const float*)d_in[4];
    const float* b1  = (const float*)d_in[5];
    const float* W2  = (const float*)d_in[6];
    const float* a2s = (const float*)d_in[7];
    const float* a2d = (const float*)d_in[8];
    const float* b2  = (const float*)d_in[9];
    float* out = (float*)d_out;

    char* p = (char*)d_ws;
    auto alloc = [&](size_t bytes) {
        char* r = p;
        p += (bytes + 255) & ~(size_t)255;
        return r;
    };
    unsigned short* h1b = (unsigned short*)alloc((size_t)N_NODES * HH * 2);
    unsigned short* h2b = (unsigned short*)alloc((size_t)N_NODES * HH * 2);
    unsigned short* h3b = (unsigned short*)alloc((size_t)N_NODES * OUT_CH * 2);
    unsigned short* w1t = (unsigned short*)alloc((size_t)IN_CH * HH * 2);
    unsigned short* w2t = (unsigned short*)alloc((size_t)NC2 * HH * 2);
    float* as1  = (float*)alloc((size_t)N_NODES * HEADS * 4);
    float* ad1  = (float*)alloc((size_t)N_NODES * HEADS * 4);
    float* as2v = (float*)alloc((size_t)N_NODES * 4);
    float* ad2v = (float*)alloc((size_t)N_NODES * 4);
    int* deg    = (int*)alloc((size_t)N_NODES * 4);
    int* pos    = (int*)alloc((size_t)E_TOT * 4);
    int* offs   = (int*)alloc((size_t)(N_NODES + 1) * 4);
    int* csr    = (int*)alloc((size_t)E_TOT * 4);

    setup_kernel<<<79 + HH + NC2, 256, 0, stream>>>(W1, W2, w1t, w2t, deg);
    hist_kernel<<<(E_TOT + 255) / 256, 256, 0, stream>>>(ei, deg, pos);
    scan_kernel<<<1, 1024, 0, stream>>>(deg, offs);
    scatter_kernel<<<(E_TOT + 255) / 256, 256, 0, stream>>>(ei, offs, pos, csr);

    gemm1<<<313 * 2, 256, 0, stream>>>(x, w1t, a1s, a1d, h1b, as1, ad1);
    aggr1<<<N_NODES / 4, 256, 0, stream>>>(h1b, as1, ad1, b1, offs, csr, h2b);
    gemm2<<<313, 256, 0, stream>>>(h2b, w2t, a2s, a2d, h3b, as2v, ad2v);
    aggr2<<<N_NODES / 4, 256, 0, stream>>>(h3b, as2v, ad2v, b2, offs, csr, out);
}